// Round 7
// baseline (24.250 us; speedup 1.0000x reference)
//
#include <hip/hip_runtime.h>
#include <math.h>

#define N_G   2048
#define W_IMG 128
#define H_IMG 128
#define NPIX  (W_IMG * H_IMG)
#define TANX  0.5f
#define TANY  0.5f
#define ALPHA_MIN (1.0f / 255.0f)
#define T_EPS_C 1e-4f
#define CAP   1024   // gathered sorted-list capacity (c beyond CAP uses exact fallback)

// One block per 8x8 tile (256 blocks = 256 CUs), 256 threads, ~152 KB LDS.
// Phase 1: preprocess ALL 2048 gaussians into LDS (8/thread), fast-math intrinsics.
// Phase 2: all 4 waves cull; unordered LDS-atomic compaction (sort re-orders anyway).
// Phase 3: local stable sort by unique key (tz, idx) == global argsort | subset;
//          scatter directly into contiguous sorted SoA arrays (kills index chains).
// Phase 4: SEGMENTED composite — 4 waves, exact two-pass:
//          pass A: per-segment transmittance products Tseg (alpha-only);
//          pass B: each wave composites its segment from exact prefix T0.
//          Gate (T>eps) and counter are exact per lane. Wave 0 reduces.
__global__ __launch_bounds__(256) void gs_fused(const float* __restrict__ means3D,
                                                const float* __restrict__ opac,
                                                const float* __restrict__ colors,
                                                const float* __restrict__ scales,
                                                const float* __restrict__ rots,
                                                const float* __restrict__ viewm,
                                                const float* __restrict__ projm,
                                                const float* __restrict__ bg,
                                                float* __restrict__ out) {
    __shared__ float4 bbx[N_G];            // px, py, ex, ey           32 KB
    __shared__ float4 pf1[N_G];            // cA, cB, cC, op           32 KB
    __shared__ float4 pf2[N_G];            // cr, cg, cb, tz           32 KB
    __shared__ unsigned short lst[N_G];    //                           4 KB
    __shared__ unsigned short srt[N_G];    //                           4 KB
    __shared__ float4 scratch4[512];       // stz | Tseg/acc/Tfin       8 KB
    __shared__ float4 sf1[CAP];            // sorted cA..op            16 KB
    __shared__ float4 sf2[CAP];            // sorted cr..tz            16 KB
    __shared__ float2 spos[CAP];           // sorted px,py              8 KB
    __shared__ int s_count;

    float* scr = (float*)scratch4;

    int tid = threadIdx.x;
    int bid = blockIdx.x;
    float* radii_out = out + 4 * NPIX;
    if (tid == 0) s_count = 0;

    // ---- Phase 1: preprocess all gaussians (8 per thread) ----
    for (int k = 0; k < N_G / 256; k++) {
        int i = k * 256 + tid;

        float mx = means3D[i * 3 + 0], my = means3D[i * 3 + 1], mz = means3D[i * 3 + 2];
        float pv0 = mx * viewm[0] + my * viewm[4] + mz * viewm[8]  + viewm[12];
        float pv1 = mx * viewm[1] + my * viewm[5] + mz * viewm[9]  + viewm[13];
        float tz  = mx * viewm[2] + my * viewm[6] + mz * viewm[10] + viewm[14];

        float ph[4];
#pragma unroll
        for (int j = 0; j < 4; j++)
            ph[j] = mx * projm[0 * 4 + j] + my * projm[1 * 4 + j] + mz * projm[2 * 4 + j] + projm[3 * 4 + j];
        float inv_w = __builtin_amdgcn_rcpf(ph[3] + 1e-7f);
        float ppx = ph[0] * inv_w, ppy = ph[1] * inv_w;

        float qr = rots[i * 4 + 0], qx = rots[i * 4 + 1], qy = rots[i * 4 + 2], qz = rots[i * 4 + 3];
        float qn = __builtin_amdgcn_rsqf(qr * qr + qx * qx + qy * qy + qz * qz);
        qr *= qn; qx *= qn; qy *= qn; qz *= qn;
        float R[3][3] = {
            {1.0f - 2.0f * (qy * qy + qz * qz), 2.0f * (qx * qy - qr * qz), 2.0f * (qx * qz + qr * qy)},
            {2.0f * (qx * qy + qr * qz), 1.0f - 2.0f * (qx * qx + qz * qz), 2.0f * (qy * qz - qr * qx)},
            {2.0f * (qx * qz - qr * qy), 2.0f * (qy * qz + qr * qx), 1.0f - 2.0f * (qx * qx + qy * qy)}};

        float sc[3] = {scales[i * 3 + 0], scales[i * 3 + 1], scales[i * 3 + 2]};
        float M[3][3];
#pragma unroll
        for (int r = 0; r < 3; r++)
#pragma unroll
            for (int cx = 0; cx < 3; cx++) M[r][cx] = R[r][cx] * sc[cx];

        float Sg[3][3];
#pragma unroll
        for (int r = 0; r < 3; r++)
#pragma unroll
            for (int kk = 0; kk < 3; kk++)
                Sg[r][kk] = M[r][0] * M[kk][0] + M[r][1] * M[kk][1] + M[r][2] * M[kk][2];

        float T1[3][3];
#pragma unroll
        for (int j = 0; j < 3; j++)
#pragma unroll
            for (int l = 0; l < 3; l++)
                T1[j][l] = Sg[j][0] * viewm[0 * 4 + l] + Sg[j][1] * viewm[1 * 4 + l] + Sg[j][2] * viewm[2 * 4 + l];
        float Cc[3][3];
#pragma unroll
        for (int r = 0; r < 3; r++)
#pragma unroll
            for (int l = 0; l < 3; l++)
                Cc[r][l] = viewm[0 * 4 + r] * T1[0][l] + viewm[1 * 4 + r] * T1[1][l] + viewm[2 * 4 + r] * T1[2][l];

        const float fx = W_IMG / (2.0f * TANX), fy = H_IMG / (2.0f * TANY);
        float invtz = __builtin_amdgcn_rcpf(tz);
        float txl = fminf(fmaxf(pv0 * invtz, -1.3f * TANX), 1.3f * TANX) * tz;
        float tyl = fminf(fmaxf(pv1 * invtz, -1.3f * TANY), 1.3f * TANY) * tz;
        float a0 = fx * invtz, a2 = -fx * txl * invtz * invtz;
        float b1 = fy * invtz, b2 = -fy * tyl * invtz * invtz;

        float c00 = a0 * a0 * Cc[0][0] + 2.0f * a0 * a2 * Cc[0][2] + a2 * a2 * Cc[2][2];
        float c11 = b1 * b1 * Cc[1][1] + 2.0f * b1 * b2 * Cc[1][2] + b2 * b2 * Cc[2][2];
        float c01 = a0 * b1 * Cc[0][1] + a0 * b2 * Cc[0][2] + a2 * b1 * Cc[1][2] + a2 * b2 * Cc[2][2];

        float a = c00 + 0.3f, c = c11 + 0.3f, b = c01;
        float det = a * c - b * b;
        bool valid = (tz > 0.2f) && (det > 0.0f);
        float det_s = (det > 0.0f) ? det : 1.0f;
        float rdet = __builtin_amdgcn_rcpf(det_s);
        float conA = c * rdet, conB = -b * rdet, conC = a * rdet;
        float mid = 0.5f * (a + c);
        float lam = mid + __builtin_amdgcn_sqrtf(fmaxf(0.1f, mid * mid - det));
        float radf = valid ? ceilf(3.0f * __builtin_amdgcn_sqrtf(lam)) : 0.0f;

        float op = opac[i];
        // alpha >= 1/255 requires d^T conic d <= 2L, L = log(255*op);
        // ellipse extents: |dx| <= sqrt(2L*a), |dy| <= sqrt(2L*c).
        float L = __logf(255.0f * op);
        float ex, ey;
        if (valid && L > 0.0f) {
            ex = __builtin_amdgcn_sqrtf(2.0f * L * a) + 2e-2f;
            ey = __builtin_amdgcn_sqrtf(2.0f * L * c) + 2e-2f;
        } else {
            ex = -1e9f; ey = -1e9f;
        }

        bbx[i] = make_float4(((ppx + 1.0f) * (float)W_IMG - 1.0f) * 0.5f,
                             ((ppy + 1.0f) * (float)H_IMG - 1.0f) * 0.5f, ex, ey);
        pf1[i] = make_float4(conA, conB, conC, op);
        pf2[i] = make_float4(colors[i * 3 + 0], colors[i * 3 + 1], colors[i * 3 + 2], tz);

        if (bid == 0) radii_out[i] = (float)(int)radf;
    }
    __syncthreads();

    int tilex = bid & 15, tiley = bid >> 4;
    int wave = tid >> 6, lane = tid & 63;

    // ---- Phase 2: cull, all 4 waves, unordered LDS-atomic compaction ----
    {
        float tx0 = (float)(tilex << 3), ty0 = (float)(tiley << 3);
        float tx1 = tx0 + 7.0f, ty1 = ty0 + 7.0f;
#pragma unroll
        for (int cc = 0; cc < 8; cc++) {
            int gi = (wave * 8 + cc) * 64 + lane;
            float4 b = bbx[gi];
            bool pred = (b.x >= tx0 - b.z) && (b.x <= tx1 + b.z) &&
                        (b.y >= ty0 - b.w) && (b.y <= ty1 + b.w);
            unsigned long long m = __ballot(pred);
            int n = (int)__popcll(m);
            int base = 0;
            if (lane == 0 && n) base = atomicAdd(&s_count, n);
            base = __shfl(base, 0);
            if (pred)
                lst[base + (int)__popcll(m & ((1ull << lane) - 1ull))] = (unsigned short)gi;
        }
    }
    __syncthreads();
    int c = s_count;

    // ---- Phase 3: stable sort by (tz, idx); scatter into sorted SoA ----
    for (int t = tid; t < c; t += 256) scr[t] = pf2[lst[t]].w;   // stz
    __syncthreads();
    for (int t = tid; t < c; t += 256) {
        int gi = lst[t];
        float my = scr[t];
        int rank = 0;
        int j = 0;
        for (; j + 4 <= c; j += 4) {
            float4 v = scratch4[j >> 2];
            int i0 = lst[j], i1 = lst[j + 1], i2 = lst[j + 2], i3 = lst[j + 3];
            rank += (v.x < my) || (v.x == my && i0 < gi);
            rank += (v.y < my) || (v.y == my && i1 < gi);
            rank += (v.z < my) || (v.z == my && i2 < gi);
            rank += (v.w < my) || (v.w == my && i3 < gi);
        }
        for (; j < c; j++) {
            float v = scr[j];
            rank += (v < my) || (v == my && lst[j] < gi);
        }
        srt[rank] = (unsigned short)gi;
        if (rank < CAP) {
            sf1[rank] = pf1[gi];
            sf2[rank] = pf2[gi];
            float4 b = bbx[gi];
            spos[rank] = make_float2(b.x, b.y);
        }
    }
    __syncthreads();   // scr (stz) dead from here; reused as Tseg/acc/Tfinal

    // ---- Phase 4: segmented composite over 4 waves ----
    float gx = (float)((tilex << 3) + (lane & 7));
    float gy = (float)((tiley << 3) + (lane >> 3));
    int seglen = (c + 3) >> 2;
    int s0 = wave * seglen;
    int s1 = min(c, s0 + seglen);

    // Pass A: per-segment transmittance product (alpha-only; no gate — matches cumprod)
    float Tw = 1.0f;
    for (int t = s0; t < s1; ++t) {
        float4 f1; float2 pp;
        if (t < CAP) { f1 = sf1[t]; pp = spos[t]; }
        else { int g = srt[t]; f1 = pf1[g]; float4 b = bbx[g]; pp = make_float2(b.x, b.y); }
        float dx = pp.x - gx, dy = pp.y - gy;
        float power = -0.5f * (f1.x * dx * dx + f1.z * dy * dy) - f1.y * dx * dy;
        if (power <= 0.0f) {
            float alpha = fminf(0.99f, f1.w * __expf(power));
            if (alpha >= ALPHA_MIN) Tw *= (1.0f - alpha);
        }
    }
    scr[wave * 64 + lane] = Tw;    // Tseg[wave][lane] in scr[0..255]
    __syncthreads();

    // Pass B: composite segment from exact prefix T0
    float T0 = 1.0f;
#pragma unroll
    for (int s = 0; s < 3; ++s) if (s < wave) T0 *= scr[s * 64 + lane];
    float T = T0, cr = 0.0f, cg = 0.0f, cb = 0.0f, dep = 0.0f;
    int cnt = 0;
    bool skip = (wave != 3) && __all(T0 <= T_EPS_C);
    if (!skip) {
        for (int t = s0; t < s1; ++t) {
            float4 f1, f2; float2 pp;
            if (t < CAP) { f1 = sf1[t]; f2 = sf2[t]; pp = spos[t]; }
            else { int g = srt[t]; f1 = pf1[g]; f2 = pf2[g]; float4 b = bbx[g]; pp = make_float2(b.x, b.y); }
            float dx = pp.x - gx, dy = pp.y - gy;
            float power = -0.5f * (f1.x * dx * dx + f1.z * dy * dy) - f1.y * dx * dy;
            if (power <= 0.0f) {
                float alpha = fminf(0.99f, f1.w * __expf(power));
                if (alpha >= ALPHA_MIN) {
                    if (T > T_EPS_C) {
                        float w = alpha * T;
                        cr += w * f2.x; cg += w * f2.y; cb += w * f2.z;
                        dep += w * f2.w;
                        cnt++;
                    }
                    T *= (1.0f - alpha);
                    if (wave != 3 && __all(T <= T_EPS_C)) break;
                }
            }
        }
    }
    scratch4[64 + wave * 64 + lane] = make_float4(cr, cg, cb, dep);  // acc in scr[256..1279]
    ((int*)(scr + 1280))[wave * 64 + lane] = cnt;                    // scr[1280..1535]
    if (wave == 3) scr[1536 + lane] = T;                             // final transmittance
    __syncthreads();

    // ---- Final: wave 0 reduces 4 partials per pixel, adds bg, writes out ----
    if (tid < 64) {
        float4 a0 = scratch4[64 + 0 * 64 + tid];
        float4 a1 = scratch4[64 + 1 * 64 + tid];
        float4 a2 = scratch4[64 + 2 * 64 + tid];
        float4 a3 = scratch4[64 + 3 * 64 + tid];
        const int* an = (const int*)(scr + 1280);
        int cnt_t = an[tid] + an[64 + tid] + an[128 + tid] + an[192 + tid];
        float Tf = scr[1536 + tid];

        float crr = a0.x + a1.x + a2.x + a3.x + Tf * bg[0];
        float cgg = a0.y + a1.y + a2.y + a3.y + Tf * bg[1];
        float cbb = a0.z + a1.z + a2.z + a3.z + Tf * bg[2];
        float dpp = a0.w + a1.w + a2.w + a3.w;

        int pid = ((tiley << 3) + (tid >> 3)) * W_IMG + (tilex << 3) + (tid & 7);
        out[0 * NPIX + pid] = crr;
        out[1 * NPIX + pid] = cgg;
        out[2 * NPIX + pid] = cbb;
        out[3 * NPIX + pid] = dpp;
        out[4 * NPIX + N_G + pid] = (float)cnt_t;
    }
}

extern "C" void kernel_launch(void* const* d_in, const int* in_sizes, int n_in,
                              void* d_out, int out_size, void* d_ws, size_t ws_size,
                              hipStream_t stream) {
    const float* bg      = (const float*)d_in[0];
    const float* means3D = (const float*)d_in[1];
    const float* opac    = (const float*)d_in[3];
    const float* colors  = (const float*)d_in[4];
    const float* scales  = (const float*)d_in[5];
    const float* rots    = (const float*)d_in[6];
    const float* viewm   = (const float*)d_in[7];
    const float* projm   = (const float*)d_in[8];

    gs_fused<<<256, 256, 0, stream>>>(means3D, opac, colors, scales, rots,
                                      viewm, projm, bg, (float*)d_out);
}

// Round 8
// 18.763 us; speedup vs baseline: 1.2924x; 1.2924x over previous
//
#include <hip/hip_runtime.h>
#include <math.h>

#define N_G   2048
#define W_IMG 128
#define H_IMG 128
#define NPIX  (W_IMG * H_IMG)
#define TANX  0.5f
#define TANY  0.5f
#define ALPHA_MIN (1.0f / 255.0f)
#define T_EPS_C 1e-4f
#define CAP   1016   // gathered sorted-list capacity (c beyond CAP -> exact srt fallback)
#define NTHR  512
#define NWAVE 8

// One block per 8x8 tile (256 blocks = 256 CUs), 512 threads = 2 waves/SIMD,
// ~160 KB LDS. TLP doubled vs R7 to hide LDS/L2 latency in every phase.
// Phase 1: preprocess ALL 2048 gaussians into LDS (4/thread), fast-math.
// Phase 2: 8 waves cull; unordered LDS-atomic compaction (sort re-orders anyway).
// Phase 3: local stable sort by unique key (tz, idx) == global argsort | subset;
//          scatter into contiguous sorted SoA arrays.
// Phase 4: SEGMENTED composite — 8 waves, exact two-pass:
//          pass A: per-segment transmittance products Tseg (alpha-only);
//          pass B: each wave composites its segment from exact prefix T0;
//          final T = product of all 8 Tseg (independent of pass B state).
__global__ __launch_bounds__(NTHR) void gs_fused(const float* __restrict__ means3D,
                                                 const float* __restrict__ opac,
                                                 const float* __restrict__ colors,
                                                 const float* __restrict__ scales,
                                                 const float* __restrict__ rots,
                                                 const float* __restrict__ viewm,
                                                 const float* __restrict__ projm,
                                                 const float* __restrict__ bg,
                                                 float* __restrict__ out) {
    __shared__ float4 bbx[N_G];            // px, py, ex, ey           32 KB
    __shared__ float4 pf1[N_G];            // cA, cB, cC, op           32 KB
    __shared__ float4 pf2[N_G];            // cr, cg, cb, tz           32 KB
    __shared__ unsigned short lst[N_G];    // cull list; cnt overlay    4 KB
    __shared__ unsigned short srt[N_G];    // sorted indices            4 KB
    __shared__ float4 scratch4[512];       // stz | Tseg                8 KB
    __shared__ float4 accv[NTHR];          // pass-B partials           8 KB
    __shared__ float4 sf1[CAP];            // sorted cA..op           15.9 KB
    __shared__ float4 sf2[CAP];            // sorted cr..tz           15.9 KB
    __shared__ float2 spos[CAP];           // sorted px,py             7.9 KB
    __shared__ int s_count;

    float* scr = (float*)scratch4;

    int tid = threadIdx.x;
    int bid = blockIdx.x;
    float* radii_out = out + 4 * NPIX;
    if (tid == 0) s_count = 0;

    // ---- Phase 1: preprocess all gaussians (4 per thread) ----
    for (int k = 0; k < N_G / NTHR; k++) {
        int i = k * NTHR + tid;

        float mx = means3D[i * 3 + 0], my = means3D[i * 3 + 1], mz = means3D[i * 3 + 2];
        float pv0 = mx * viewm[0] + my * viewm[4] + mz * viewm[8]  + viewm[12];
        float pv1 = mx * viewm[1] + my * viewm[5] + mz * viewm[9]  + viewm[13];
        float tz  = mx * viewm[2] + my * viewm[6] + mz * viewm[10] + viewm[14];

        float ph[4];
#pragma unroll
        for (int j = 0; j < 4; j++)
            ph[j] = mx * projm[0 * 4 + j] + my * projm[1 * 4 + j] + mz * projm[2 * 4 + j] + projm[3 * 4 + j];
        float inv_w = __builtin_amdgcn_rcpf(ph[3] + 1e-7f);
        float ppx = ph[0] * inv_w, ppy = ph[1] * inv_w;

        float qr = rots[i * 4 + 0], qx = rots[i * 4 + 1], qy = rots[i * 4 + 2], qz = rots[i * 4 + 3];
        float qn = __builtin_amdgcn_rsqf(qr * qr + qx * qx + qy * qy + qz * qz);
        qr *= qn; qx *= qn; qy *= qn; qz *= qn;
        float R[3][3] = {
            {1.0f - 2.0f * (qy * qy + qz * qz), 2.0f * (qx * qy - qr * qz), 2.0f * (qx * qz + qr * qy)},
            {2.0f * (qx * qy + qr * qz), 1.0f - 2.0f * (qx * qx + qz * qz), 2.0f * (qy * qz - qr * qx)},
            {2.0f * (qx * qz - qr * qy), 2.0f * (qy * qz + qr * qx), 1.0f - 2.0f * (qx * qx + qy * qy)}};

        float sc[3] = {scales[i * 3 + 0], scales[i * 3 + 1], scales[i * 3 + 2]};
        float M[3][3];
#pragma unroll
        for (int r = 0; r < 3; r++)
#pragma unroll
            for (int cx = 0; cx < 3; cx++) M[r][cx] = R[r][cx] * sc[cx];

        float Sg[3][3];
#pragma unroll
        for (int r = 0; r < 3; r++)
#pragma unroll
            for (int kk = 0; kk < 3; kk++)
                Sg[r][kk] = M[r][0] * M[kk][0] + M[r][1] * M[kk][1] + M[r][2] * M[kk][2];

        float T1[3][3];
#pragma unroll
        for (int j = 0; j < 3; j++)
#pragma unroll
            for (int l = 0; l < 3; l++)
                T1[j][l] = Sg[j][0] * viewm[0 * 4 + l] + Sg[j][1] * viewm[1 * 4 + l] + Sg[j][2] * viewm[2 * 4 + l];
        float Cc[3][3];
#pragma unroll
        for (int r = 0; r < 3; r++)
#pragma unroll
            for (int l = 0; l < 3; l++)
                Cc[r][l] = viewm[0 * 4 + r] * T1[0][l] + viewm[1 * 4 + r] * T1[1][l] + viewm[2 * 4 + r] * T1[2][l];

        const float fx = W_IMG / (2.0f * TANX), fy = H_IMG / (2.0f * TANY);
        float invtz = __builtin_amdgcn_rcpf(tz);
        float txl = fminf(fmaxf(pv0 * invtz, -1.3f * TANX), 1.3f * TANX) * tz;
        float tyl = fminf(fmaxf(pv1 * invtz, -1.3f * TANY), 1.3f * TANY) * tz;
        float a0 = fx * invtz, a2 = -fx * txl * invtz * invtz;
        float b1 = fy * invtz, b2 = -fy * tyl * invtz * invtz;

        float c00 = a0 * a0 * Cc[0][0] + 2.0f * a0 * a2 * Cc[0][2] + a2 * a2 * Cc[2][2];
        float c11 = b1 * b1 * Cc[1][1] + 2.0f * b1 * b2 * Cc[1][2] + b2 * b2 * Cc[2][2];
        float c01 = a0 * b1 * Cc[0][1] + a0 * b2 * Cc[0][2] + a2 * b1 * Cc[1][2] + a2 * b2 * Cc[2][2];

        float a = c00 + 0.3f, c = c11 + 0.3f, b = c01;
        float det = a * c - b * b;
        bool valid = (tz > 0.2f) && (det > 0.0f);
        float det_s = (det > 0.0f) ? det : 1.0f;
        float rdet = __builtin_amdgcn_rcpf(det_s);
        float conA = c * rdet, conB = -b * rdet, conC = a * rdet;
        float mid = 0.5f * (a + c);
        float lam = mid + __builtin_amdgcn_sqrtf(fmaxf(0.1f, mid * mid - det));
        float radf = valid ? ceilf(3.0f * __builtin_amdgcn_sqrtf(lam)) : 0.0f;

        float op = opac[i];
        // alpha >= 1/255 requires d^T conic d <= 2L, L = log(255*op);
        // ellipse extents: |dx| <= sqrt(2L*a), |dy| <= sqrt(2L*c).
        float L = __logf(255.0f * op);
        float ex, ey;
        if (valid && L > 0.0f) {
            ex = __builtin_amdgcn_sqrtf(2.0f * L * a) + 2e-2f;
            ey = __builtin_amdgcn_sqrtf(2.0f * L * c) + 2e-2f;
        } else {
            ex = -1e9f; ey = -1e9f;
        }

        bbx[i] = make_float4(((ppx + 1.0f) * (float)W_IMG - 1.0f) * 0.5f,
                             ((ppy + 1.0f) * (float)H_IMG - 1.0f) * 0.5f, ex, ey);
        pf1[i] = make_float4(conA, conB, conC, op);
        pf2[i] = make_float4(colors[i * 3 + 0], colors[i * 3 + 1], colors[i * 3 + 2], tz);

        if (bid == 0) radii_out[i] = (float)(int)radf;
    }
    __syncthreads();

    int tilex = bid & 15, tiley = bid >> 4;
    int wave = tid >> 6, lane = tid & 63;

    // ---- Phase 2: cull, 8 waves x 4 chunks, unordered LDS-atomic compaction ----
    {
        float tx0 = (float)(tilex << 3), ty0 = (float)(tiley << 3);
        float tx1 = tx0 + 7.0f, ty1 = ty0 + 7.0f;
#pragma unroll
        for (int cc = 0; cc < 4; cc++) {
            int gi = (wave * 4 + cc) * 64 + lane;
            float4 b = bbx[gi];
            bool pred = (b.x >= tx0 - b.z) && (b.x <= tx1 + b.z) &&
                        (b.y >= ty0 - b.w) && (b.y <= ty1 + b.w);
            unsigned long long m = __ballot(pred);
            int n = (int)__popcll(m);
            int base = 0;
            if (lane == 0 && n) base = atomicAdd(&s_count, n);
            base = __shfl(base, 0);
            if (pred)
                lst[base + (int)__popcll(m & ((1ull << lane) - 1ull))] = (unsigned short)gi;
        }
    }
    __syncthreads();
    int c = s_count;

    // ---- Phase 3: stable sort by (tz, idx); scatter into sorted SoA ----
    for (int t = tid; t < c; t += NTHR) scr[t] = pf2[lst[t]].w;   // stz
    __syncthreads();
    for (int t = tid; t < c; t += NTHR) {
        int gi = lst[t];
        float my = scr[t];
        int rank = 0;
        int j = 0;
        for (; j + 4 <= c; j += 4) {
            float4 v = scratch4[j >> 2];
            int i0 = lst[j], i1 = lst[j + 1], i2 = lst[j + 2], i3 = lst[j + 3];
            rank += (v.x < my) || (v.x == my && i0 < gi);
            rank += (v.y < my) || (v.y == my && i1 < gi);
            rank += (v.z < my) || (v.z == my && i2 < gi);
            rank += (v.w < my) || (v.w == my && i3 < gi);
        }
        for (; j < c; j++) {
            float v = scr[j];
            rank += (v < my) || (v == my && lst[j] < gi);
        }
        srt[rank] = (unsigned short)gi;
        if (rank < CAP) {
            sf1[rank] = pf1[gi];
            sf2[rank] = pf2[gi];
            float4 b = bbx[gi];
            spos[rank] = make_float2(b.x, b.y);
        }
    }
    __syncthreads();   // scr (stz) dead from here; reused as Tseg

    // ---- Phase 4: segmented composite over 8 waves ----
    float gx = (float)((tilex << 3) + (lane & 7));
    float gy = (float)((tiley << 3) + (lane >> 3));
    int seglen = (c + NWAVE - 1) / NWAVE;
    int s0 = wave * seglen;
    int s1 = min(c, s0 + seglen);

    // Pass A: per-segment transmittance product (alpha-only; matches cumprod)
    float Tw = 1.0f;
    for (int t = s0; t < s1; ++t) {
        float4 f1; float2 pp;
        if (t < CAP) { f1 = sf1[t]; pp = spos[t]; }
        else { int g = srt[t]; f1 = pf1[g]; float4 b = bbx[g]; pp = make_float2(b.x, b.y); }
        float dx = pp.x - gx, dy = pp.y - gy;
        float power = -0.5f * (f1.x * dx * dx + f1.z * dy * dy) - f1.y * dx * dy;
        if (power <= 0.0f) {
            float alpha = fminf(0.99f, f1.w * __expf(power));
            if (alpha >= ALPHA_MIN) Tw *= (1.0f - alpha);
        }
    }
    scr[wave * 64 + lane] = Tw;    // Tseg[wave][lane] in scr[0..511]
    __syncthreads();

    // Pass B: composite segment from exact prefix T0
    float T0 = 1.0f;
#pragma unroll
    for (int s = 0; s < NWAVE - 1; ++s) if (s < wave) T0 *= scr[s * 64 + lane];
    float T = T0, cr = 0.0f, cg = 0.0f, cb = 0.0f, dep = 0.0f;
    int cnt = 0;
    if (!__all(T0 <= T_EPS_C)) {
        for (int t = s0; t < s1; ++t) {
            float4 f1, f2; float2 pp;
            if (t < CAP) { f1 = sf1[t]; f2 = sf2[t]; pp = spos[t]; }
            else { int g = srt[t]; f1 = pf1[g]; f2 = pf2[g]; float4 b = bbx[g]; pp = make_float2(b.x, b.y); }
            float dx = pp.x - gx, dy = pp.y - gy;
            float power = -0.5f * (f1.x * dx * dx + f1.z * dy * dy) - f1.y * dx * dy;
            if (power <= 0.0f) {
                float alpha = fminf(0.99f, f1.w * __expf(power));
                if (alpha >= ALPHA_MIN) {
                    if (T > T_EPS_C) {
                        float w = alpha * T;
                        cr += w * f2.x; cg += w * f2.y; cb += w * f2.z;
                        dep += w * f2.w;
                        cnt++;
                    }
                    T *= (1.0f - alpha);
                    if (__all(T <= T_EPS_C)) break;   // exact: later waves use Tseg only
                }
            }
        }
    }
    accv[wave * 64 + lane] = make_float4(cr, cg, cb, dep);
    ((int*)lst)[wave * 64 + lane] = cnt;    // lst dead after sort: overlay
    __syncthreads();

    // ---- Final: wave 0 reduces 8 partials per pixel, adds bg, writes out ----
    if (tid < 64) {
        float crr = 0.0f, cgg = 0.0f, cbb = 0.0f, dpp = 0.0f, Tf = 1.0f;
        int cnt_t = 0;
        const int* an = (const int*)lst;
#pragma unroll
        for (int s = 0; s < NWAVE; ++s) {
            float4 a = accv[s * 64 + tid];
            crr += a.x; cgg += a.y; cbb += a.z; dpp += a.w;
            cnt_t += an[s * 64 + tid];
            Tf *= scr[s * 64 + tid];
        }
        crr += Tf * bg[0]; cgg += Tf * bg[1]; cbb += Tf * bg[2];

        int pid = ((tiley << 3) + (tid >> 3)) * W_IMG + (tilex << 3) + (tid & 7);
        out[0 * NPIX + pid] = crr;
        out[1 * NPIX + pid] = cgg;
        out[2 * NPIX + pid] = cbb;
        out[3 * NPIX + pid] = dpp;
        out[4 * NPIX + N_G + pid] = (float)cnt_t;
    }
}

extern "C" void kernel_launch(void* const* d_in, const int* in_sizes, int n_in,
                              void* d_out, int out_size, void* d_ws, size_t ws_size,
                              hipStream_t stream) {
    const float* bg      = (const float*)d_in[0];
    const float* means3D = (const float*)d_in[1];
    const float* opac    = (const float*)d_in[3];
    const float* colors  = (const float*)d_in[4];
    const float* scales  = (const float*)d_in[5];
    const float* rots    = (const float*)d_in[6];
    const float* viewm   = (const float*)d_in[7];
    const float* projm   = (const float*)d_in[8];

    gs_fused<<<256, NTHR, 0, stream>>>(means3D, opac, colors, scales, rots,
                                       viewm, projm, bg, (float*)d_out);
}

// Round 9
// 17.627 us; speedup vs baseline: 1.3757x; 1.0644x over previous
//
#include <hip/hip_runtime.h>
#include <math.h>

#define N_G   2048
#define W_IMG 128
#define H_IMG 128
#define NPIX  (W_IMG * H_IMG)
#define TANX  0.5f
#define TANY  0.5f
#define ALPHA_MIN (1.0f / 255.0f)
#define T_EPS_C 1e-4f
#define NTHR  1024
#define NWAVE 16

// One block per 8x8 tile (256 blocks = 256 CUs), 1024 threads = 4 waves/SIMD,
// 128 KB LDS (1 block/CU). R8 proved latency-bound + TLP is the lever: 2 waves/SIMD
// gave -25%; this doubles TLP again.
// Phase 1: preprocess ALL 2048 gaussians into LDS (2/thread), fast-math.
// Phase 2: 16 waves cull; unordered LDS-atomic compaction (sort re-orders anyway).
// Phase 3: local stable sort by unique key (tz, idx) == global argsort | subset.
// Phase 4: SEGMENTED composite — 16 waves, exact two-pass:
//          pass A: per-segment transmittance products Tseg (alpha-only);
//          pass B: each wave composites its segment from exact prefix T0;
//          final T = product of all 16 Tseg (independent of pass-B early exit).
__global__ __launch_bounds__(NTHR) void gs_fused(const float* __restrict__ means3D,
                                                 const float* __restrict__ opac,
                                                 const float* __restrict__ colors,
                                                 const float* __restrict__ scales,
                                                 const float* __restrict__ rots,
                                                 const float* __restrict__ viewm,
                                                 const float* __restrict__ projm,
                                                 const float* __restrict__ bg,
                                                 float* __restrict__ out) {
    __shared__ float4 bbx[N_G];            // px, py, ex, ey           32 KB
    __shared__ float4 pf1[N_G];            // cA, cB, cC, op           32 KB
    __shared__ float4 pf2[N_G];            // cr, cg, cb, tz           32 KB
    __shared__ unsigned short lst[N_G];    // cull list; cnt overlay    4 KB
    __shared__ unsigned short srt[N_G];    // sorted indices            4 KB
    __shared__ float4 scratch4[512];       // stz | Tseg                8 KB
    __shared__ float4 accv[NTHR];          // pass-B partials          16 KB
    __shared__ int s_count;

    float* scr = (float*)scratch4;

    int tid = threadIdx.x;
    int bid = blockIdx.x;
    float* radii_out = out + 4 * NPIX;
    if (tid == 0) s_count = 0;

    // ---- Phase 1: preprocess all gaussians (2 per thread) ----
#pragma unroll
    for (int k = 0; k < N_G / NTHR; k++) {
        int i = k * NTHR + tid;

        float mx = means3D[i * 3 + 0], my = means3D[i * 3 + 1], mz = means3D[i * 3 + 2];
        float pv0 = mx * viewm[0] + my * viewm[4] + mz * viewm[8]  + viewm[12];
        float pv1 = mx * viewm[1] + my * viewm[5] + mz * viewm[9]  + viewm[13];
        float tz  = mx * viewm[2] + my * viewm[6] + mz * viewm[10] + viewm[14];

        float ph[4];
#pragma unroll
        for (int j = 0; j < 4; j++)
            ph[j] = mx * projm[0 * 4 + j] + my * projm[1 * 4 + j] + mz * projm[2 * 4 + j] + projm[3 * 4 + j];
        float inv_w = __builtin_amdgcn_rcpf(ph[3] + 1e-7f);
        float ppx = ph[0] * inv_w, ppy = ph[1] * inv_w;

        float qr = rots[i * 4 + 0], qx = rots[i * 4 + 1], qy = rots[i * 4 + 2], qz = rots[i * 4 + 3];
        float qn = __builtin_amdgcn_rsqf(qr * qr + qx * qx + qy * qy + qz * qz);
        qr *= qn; qx *= qn; qy *= qn; qz *= qn;
        float R[3][3] = {
            {1.0f - 2.0f * (qy * qy + qz * qz), 2.0f * (qx * qy - qr * qz), 2.0f * (qx * qz + qr * qy)},
            {2.0f * (qx * qy + qr * qz), 1.0f - 2.0f * (qx * qx + qz * qz), 2.0f * (qy * qz - qr * qx)},
            {2.0f * (qx * qz - qr * qy), 2.0f * (qy * qz + qr * qx), 1.0f - 2.0f * (qx * qx + qy * qy)}};

        float sc[3] = {scales[i * 3 + 0], scales[i * 3 + 1], scales[i * 3 + 2]};
        float M[3][3];
#pragma unroll
        for (int r = 0; r < 3; r++)
#pragma unroll
            for (int cx = 0; cx < 3; cx++) M[r][cx] = R[r][cx] * sc[cx];

        float Sg[3][3];
#pragma unroll
        for (int r = 0; r < 3; r++)
#pragma unroll
            for (int kk = 0; kk < 3; kk++)
                Sg[r][kk] = M[r][0] * M[kk][0] + M[r][1] * M[kk][1] + M[r][2] * M[kk][2];

        float T1[3][3];
#pragma unroll
        for (int j = 0; j < 3; j++)
#pragma unroll
            for (int l = 0; l < 3; l++)
                T1[j][l] = Sg[j][0] * viewm[0 * 4 + l] + Sg[j][1] * viewm[1 * 4 + l] + Sg[j][2] * viewm[2 * 4 + l];
        float Cc[3][3];
#pragma unroll
        for (int r = 0; r < 3; r++)
#pragma unroll
            for (int l = 0; l < 3; l++)
                Cc[r][l] = viewm[0 * 4 + r] * T1[0][l] + viewm[1 * 4 + r] * T1[1][l] + viewm[2 * 4 + r] * T1[2][l];

        const float fx = W_IMG / (2.0f * TANX), fy = H_IMG / (2.0f * TANY);
        float invtz = __builtin_amdgcn_rcpf(tz);
        float txl = fminf(fmaxf(pv0 * invtz, -1.3f * TANX), 1.3f * TANX) * tz;
        float tyl = fminf(fmaxf(pv1 * invtz, -1.3f * TANY), 1.3f * TANY) * tz;
        float a0 = fx * invtz, a2 = -fx * txl * invtz * invtz;
        float b1 = fy * invtz, b2 = -fy * tyl * invtz * invtz;

        float c00 = a0 * a0 * Cc[0][0] + 2.0f * a0 * a2 * Cc[0][2] + a2 * a2 * Cc[2][2];
        float c11 = b1 * b1 * Cc[1][1] + 2.0f * b1 * b2 * Cc[1][2] + b2 * b2 * Cc[2][2];
        float c01 = a0 * b1 * Cc[0][1] + a0 * b2 * Cc[0][2] + a2 * b1 * Cc[1][2] + a2 * b2 * Cc[2][2];

        float a = c00 + 0.3f, c = c11 + 0.3f, b = c01;
        float det = a * c - b * b;
        bool valid = (tz > 0.2f) && (det > 0.0f);
        float det_s = (det > 0.0f) ? det : 1.0f;
        float rdet = __builtin_amdgcn_rcpf(det_s);
        float conA = c * rdet, conB = -b * rdet, conC = a * rdet;
        float mid = 0.5f * (a + c);
        float lam = mid + __builtin_amdgcn_sqrtf(fmaxf(0.1f, mid * mid - det));
        float radf = valid ? ceilf(3.0f * __builtin_amdgcn_sqrtf(lam)) : 0.0f;

        float op = opac[i];
        // alpha >= 1/255 requires d^T conic d <= 2L, L = log(255*op);
        // ellipse extents: |dx| <= sqrt(2L*a), |dy| <= sqrt(2L*c).
        float L = __logf(255.0f * op);
        float ex, ey;
        if (valid && L > 0.0f) {
            ex = __builtin_amdgcn_sqrtf(2.0f * L * a) + 2e-2f;
            ey = __builtin_amdgcn_sqrtf(2.0f * L * c) + 2e-2f;
        } else {
            ex = -1e9f; ey = -1e9f;
        }

        bbx[i] = make_float4(((ppx + 1.0f) * (float)W_IMG - 1.0f) * 0.5f,
                             ((ppy + 1.0f) * (float)H_IMG - 1.0f) * 0.5f, ex, ey);
        pf1[i] = make_float4(conA, conB, conC, op);
        pf2[i] = make_float4(colors[i * 3 + 0], colors[i * 3 + 1], colors[i * 3 + 2], tz);

        if (bid == 0) radii_out[i] = (float)(int)radf;
    }
    __syncthreads();

    int tilex = bid & 15, tiley = bid >> 4;
    int wave = tid >> 6, lane = tid & 63;

    // ---- Phase 2: cull, 16 waves x 2 chunks, unordered LDS-atomic compaction ----
    {
        float tx0 = (float)(tilex << 3), ty0 = (float)(tiley << 3);
        float tx1 = tx0 + 7.0f, ty1 = ty0 + 7.0f;
#pragma unroll
        for (int cc = 0; cc < 2; cc++) {
            int gi = (wave * 2 + cc) * 64 + lane;
            float4 b = bbx[gi];
            bool pred = (b.x >= tx0 - b.z) && (b.x <= tx1 + b.z) &&
                        (b.y >= ty0 - b.w) && (b.y <= ty1 + b.w);
            unsigned long long m = __ballot(pred);
            int n = (int)__popcll(m);
            int base = 0;
            if (lane == 0 && n) base = atomicAdd(&s_count, n);
            base = __shfl(base, 0);
            if (pred)
                lst[base + (int)__popcll(m & ((1ull << lane) - 1ull))] = (unsigned short)gi;
        }
    }
    __syncthreads();
    int c = s_count;

    // ---- Phase 3: stable sort by (tz, idx) -> srt ----
    for (int t = tid; t < c; t += NTHR) scr[t] = pf2[lst[t]].w;   // stz
    __syncthreads();
    for (int t = tid; t < c; t += NTHR) {
        int gi = lst[t];
        float my = scr[t];
        int rank = 0;
        int j = 0;
        for (; j + 4 <= c; j += 4) {
            float4 v = scratch4[j >> 2];
            int i0 = lst[j], i1 = lst[j + 1], i2 = lst[j + 2], i3 = lst[j + 3];
            rank += (v.x < my) || (v.x == my && i0 < gi);
            rank += (v.y < my) || (v.y == my && i1 < gi);
            rank += (v.z < my) || (v.z == my && i2 < gi);
            rank += (v.w < my) || (v.w == my && i3 < gi);
        }
        for (; j < c; j++) {
            float v = scr[j];
            rank += (v < my) || (v == my && lst[j] < gi);
        }
        srt[rank] = (unsigned short)gi;
    }
    __syncthreads();   // scr (stz) dead from here; reused as Tseg

    // ---- Phase 4: segmented composite over 16 waves ----
    float gx = (float)((tilex << 3) + (lane & 7));
    float gy = (float)((tiley << 3) + (lane >> 3));
    int seglen = (c + NWAVE - 1) / NWAVE;
    int s0 = wave * seglen;
    int s1 = min(c, s0 + seglen);

    // Pass A: per-segment transmittance product (alpha-only; matches cumprod)
    float Tw = 1.0f;
    for (int t = s0; t < s1; ++t) {
        int g = srt[t];
        float4 f1 = pf1[g];
        float4 b = bbx[g];
        float dx = b.x - gx, dy = b.y - gy;
        float power = -0.5f * (f1.x * dx * dx + f1.z * dy * dy) - f1.y * dx * dy;
        if (power <= 0.0f) {
            float alpha = fminf(0.99f, f1.w * __expf(power));
            if (alpha >= ALPHA_MIN) Tw *= (1.0f - alpha);
        }
    }
    scr[wave * 64 + lane] = Tw;    // Tseg[wave][lane] in scr[0..1023]
    __syncthreads();

    // Pass B: composite segment from exact prefix T0
    float T0 = 1.0f;
#pragma unroll
    for (int s = 0; s < NWAVE - 1; ++s) if (s < wave) T0 *= scr[s * 64 + lane];
    float T = T0, cr = 0.0f, cg = 0.0f, cb = 0.0f, dep = 0.0f;
    int cnt = 0;
    if (!__all(T0 <= T_EPS_C)) {
        for (int t = s0; t < s1; ++t) {
            int g = srt[t];
            float4 f1 = pf1[g];
            float4 f2 = pf2[g];
            float4 b = bbx[g];
            float dx = b.x - gx, dy = b.y - gy;
            float power = -0.5f * (f1.x * dx * dx + f1.z * dy * dy) - f1.y * dx * dy;
            if (power <= 0.0f) {
                float alpha = fminf(0.99f, f1.w * __expf(power));
                if (alpha >= ALPHA_MIN) {
                    if (T > T_EPS_C) {
                        float w = alpha * T;
                        cr += w * f2.x; cg += w * f2.y; cb += w * f2.z;
                        dep += w * f2.w;
                        cnt++;
                    }
                    T *= (1.0f - alpha);
                    if (__all(T <= T_EPS_C)) break;   // exact: T monotone; final T from Tseg
                }
            }
        }
    }
    accv[wave * 64 + lane] = make_float4(cr, cg, cb, dep);
    ((int*)lst)[wave * 64 + lane] = cnt;    // lst dead after sort: overlay (1024 ints = 4 KB)
    __syncthreads();

    // ---- Final: wave 0 reduces 16 partials per pixel, adds bg, writes out ----
    if (tid < 64) {
        float crr = 0.0f, cgg = 0.0f, cbb = 0.0f, dpp = 0.0f, Tf = 1.0f;
        int cnt_t = 0;
        const int* an = (const int*)lst;
#pragma unroll
        for (int s = 0; s < NWAVE; ++s) {
            float4 a = accv[s * 64 + tid];
            crr += a.x; cgg += a.y; cbb += a.z; dpp += a.w;
            cnt_t += an[s * 64 + tid];
            Tf *= scr[s * 64 + tid];
        }
        crr += Tf * bg[0]; cgg += Tf * bg[1]; cbb += Tf * bg[2];

        int pid = ((tiley << 3) + (tid >> 3)) * W_IMG + (tilex << 3) + (tid & 7);
        out[0 * NPIX + pid] = crr;
        out[1 * NPIX + pid] = cgg;
        out[2 * NPIX + pid] = cbb;
        out[3 * NPIX + pid] = dpp;
        out[4 * NPIX + N_G + pid] = (float)cnt_t;
    }
}

extern "C" void kernel_launch(void* const* d_in, const int* in_sizes, int n_in,
                              void* d_out, int out_size, void* d_ws, size_t ws_size,
                              hipStream_t stream) {
    const float* bg      = (const float*)d_in[0];
    const float* means3D = (const float*)d_in[1];
    const float* opac    = (const float*)d_in[3];
    const float* colors  = (const float*)d_in[4];
    const float* scales  = (const float*)d_in[5];
    const float* rots    = (const float*)d_in[6];
    const float* viewm   = (const float*)d_in[7];
    const float* projm   = (const float*)d_in[8];

    gs_fused<<<256, NTHR, 0, stream>>>(means3D, opac, colors, scales, rots,
                                       viewm, projm, bg, (float*)d_out);
}

// Round 10
// 14.789 us; speedup vs baseline: 1.6398x; 1.1920x over previous
//
#include <hip/hip_runtime.h>
#include <math.h>

#define N_G   2048
#define W_IMG 128
#define H_IMG 128
#define NPIX  (W_IMG * H_IMG)
#define TANX  0.5f
#define TANY  0.5f
#define ALPHA_MIN (1.0f / 255.0f)
#define T_EPS_C 1e-4f
#define NTHR  1024
#define NWAVE 16
#define CAP   1024

// Full per-gaussian chain (identical math to R9 phase 1, fast intrinsics).
// Outputs f1=(conA,conB,conC,op_eff), f2=(cr,cg,cb,tz), radf.
// op_eff=0 when invalid -> alpha=0 everywhere (matches reference's valid mask).
__device__ __forceinline__ void full_chain(int i,
        const float* __restrict__ means3D, const float* __restrict__ opac,
        const float* __restrict__ colors, const float* __restrict__ scales,
        const float* __restrict__ rots, const float* __restrict__ viewm,
        const float* __restrict__ projm,
        float4& f1, float4& f2, float& radf) {
    float mx = means3D[i * 3 + 0], my = means3D[i * 3 + 1], mz = means3D[i * 3 + 2];
    float pv0 = mx * viewm[0] + my * viewm[4] + mz * viewm[8]  + viewm[12];
    float pv1 = mx * viewm[1] + my * viewm[5] + mz * viewm[9]  + viewm[13];
    float tz  = mx * viewm[2] + my * viewm[6] + mz * viewm[10] + viewm[14];

    float qr = rots[i * 4 + 0], qx = rots[i * 4 + 1], qy = rots[i * 4 + 2], qz = rots[i * 4 + 3];
    float qn = __builtin_amdgcn_rsqf(qr * qr + qx * qx + qy * qy + qz * qz);
    qr *= qn; qx *= qn; qy *= qn; qz *= qn;
    float R[3][3] = {
        {1.0f - 2.0f * (qy * qy + qz * qz), 2.0f * (qx * qy - qr * qz), 2.0f * (qx * qz + qr * qy)},
        {2.0f * (qx * qy + qr * qz), 1.0f - 2.0f * (qx * qx + qz * qz), 2.0f * (qy * qz - qr * qx)},
        {2.0f * (qx * qz - qr * qy), 2.0f * (qy * qz + qr * qx), 1.0f - 2.0f * (qx * qx + qy * qy)}};

    float sc[3] = {scales[i * 3 + 0], scales[i * 3 + 1], scales[i * 3 + 2]};
    float M[3][3];
#pragma unroll
    for (int r = 0; r < 3; r++)
#pragma unroll
        for (int cx = 0; cx < 3; cx++) M[r][cx] = R[r][cx] * sc[cx];

    float Sg[3][3];
#pragma unroll
    for (int r = 0; r < 3; r++)
#pragma unroll
        for (int kk = 0; kk < 3; kk++)
            Sg[r][kk] = M[r][0] * M[kk][0] + M[r][1] * M[kk][1] + M[r][2] * M[kk][2];

    float T1[3][3];
#pragma unroll
    for (int j = 0; j < 3; j++)
#pragma unroll
        for (int l = 0; l < 3; l++)
            T1[j][l] = Sg[j][0] * viewm[0 * 4 + l] + Sg[j][1] * viewm[1 * 4 + l] + Sg[j][2] * viewm[2 * 4 + l];
    float Cc[3][3];
#pragma unroll
    for (int r = 0; r < 3; r++)
#pragma unroll
        for (int l = 0; l < 3; l++)
            Cc[r][l] = viewm[0 * 4 + r] * T1[0][l] + viewm[1 * 4 + r] * T1[1][l] + viewm[2 * 4 + r] * T1[2][l];

    const float fx = W_IMG / (2.0f * TANX), fy = H_IMG / (2.0f * TANY);
    float invtz = __builtin_amdgcn_rcpf(tz);
    float txl = fminf(fmaxf(pv0 * invtz, -1.3f * TANX), 1.3f * TANX) * tz;
    float tyl = fminf(fmaxf(pv1 * invtz, -1.3f * TANY), 1.3f * TANY) * tz;
    float a0 = fx * invtz, a2 = -fx * txl * invtz * invtz;
    float b1 = fy * invtz, b2 = -fy * tyl * invtz * invtz;

    float c00 = a0 * a0 * Cc[0][0] + 2.0f * a0 * a2 * Cc[0][2] + a2 * a2 * Cc[2][2];
    float c11 = b1 * b1 * Cc[1][1] + 2.0f * b1 * b2 * Cc[1][2] + b2 * b2 * Cc[2][2];
    float c01 = a0 * b1 * Cc[0][1] + a0 * b2 * Cc[0][2] + a2 * b1 * Cc[1][2] + a2 * b2 * Cc[2][2];

    float a = c00 + 0.3f, c = c11 + 0.3f, b = c01;
    float det = a * c - b * b;
    bool valid = (tz > 0.2f) && (det > 0.0f);
    float det_s = (det > 0.0f) ? det : 1.0f;
    float rdet = __builtin_amdgcn_rcpf(det_s);
    float conA = c * rdet, conB = -b * rdet, conC = a * rdet;
    float mid = 0.5f * (a + c);
    float lam = mid + __builtin_amdgcn_sqrtf(fmaxf(0.1f, mid * mid - det));
    radf = valid ? ceilf(3.0f * __builtin_amdgcn_sqrtf(lam)) : 0.0f;

    float op = opac[i];
    f1 = make_float4(conA, conB, conC, valid ? op : 0.0f);
    f2 = make_float4(colors[i * 3 + 0], colors[i * 3 + 1], colors[i * 3 + 2], tz);
}

// One block per 8x8 tile, 1024 threads, ~104 KB LDS.
// Phase 0: CHEAP bound per gaussian (proj + conservative alpha-extent), ~90 inst.
// Phase A: cull on bound (16 waves, unordered atomic compaction).
// Phase B: stable sort candidates by (tz, idx); FULL preprocess candidates only;
//          scatter into sorted SoA. Radii: 8 exact full-chains per block.
// Phase C: segmented composite over 16 waves (exact two-pass, as R9).
__global__ __launch_bounds__(NTHR) void gs_fused(const float* __restrict__ means3D,
                                                 const float* __restrict__ opac,
                                                 const float* __restrict__ colors,
                                                 const float* __restrict__ scales,
                                                 const float* __restrict__ rots,
                                                 const float* __restrict__ viewm,
                                                 const float* __restrict__ projm,
                                                 const float* __restrict__ bg,
                                                 float* __restrict__ out) {
    __shared__ float4 bbx[N_G];            // px, py, exb, eyb         32 KB
    __shared__ float  tzv[N_G];            //                           8 KB
    __shared__ unsigned short lst[N_G];    // cull list; cnt overlay    4 KB
    __shared__ float4 sf1[CAP];            // sorted conic+op          16 KB
    __shared__ float4 sf2[CAP];            // sorted color+tz          16 KB
    __shared__ float2 spos[CAP];           // sorted px,py              8 KB
    __shared__ float4 scratch4[CAP / 4];   // stz | Tseg                4 KB
    __shared__ float4 accv[NTHR];          // pass-B partials          16 KB
    __shared__ int s_count;

    float* scr = (float*)scratch4;
    int tid = threadIdx.x;
    int bid = blockIdx.x;
    float* radii_out = out + 4 * NPIX;
    if (tid == 0) s_count = 0;

    // view-rotation norm bound: lambda_max(W^T W) <= ||W||_1 * ||W||_inf
    float cs0 = fabsf(viewm[0]) + fabsf(viewm[4]) + fabsf(viewm[8]);
    float cs1 = fabsf(viewm[1]) + fabsf(viewm[5]) + fabsf(viewm[9]);
    float cs2 = fabsf(viewm[2]) + fabsf(viewm[6]) + fabsf(viewm[10]);
    float rs0 = fabsf(viewm[0]) + fabsf(viewm[1]) + fabsf(viewm[2]);
    float rs1 = fabsf(viewm[4]) + fabsf(viewm[5]) + fabsf(viewm[6]);
    float rs2 = fabsf(viewm[8]) + fabsf(viewm[9]) + fabsf(viewm[10]);
    float wb2 = fmaxf(cs0, fmaxf(cs1, cs2)) * fmaxf(rs0, fmaxf(rs1, rs2));

    // ---- Phase 0: cheap bound for all gaussians (2 per thread) ----
#pragma unroll
    for (int k = 0; k < N_G / NTHR; k++) {
        int i = k * NTHR + tid;
        float mx = means3D[i * 3 + 0], my = means3D[i * 3 + 1], mz = means3D[i * 3 + 2];
        float pv0 = mx * viewm[0] + my * viewm[4] + mz * viewm[8]  + viewm[12];
        float pv1 = mx * viewm[1] + my * viewm[5] + mz * viewm[9]  + viewm[13];
        float tz  = mx * viewm[2] + my * viewm[6] + mz * viewm[10] + viewm[14];

        float ph[4];
#pragma unroll
        for (int j = 0; j < 4; j++)
            ph[j] = mx * projm[0 * 4 + j] + my * projm[1 * 4 + j] + mz * projm[2 * 4 + j] + projm[3 * 4 + j];
        float inv_w = __builtin_amdgcn_rcpf(ph[3] + 1e-7f);
        float px = ((ph[0] * inv_w + 1.0f) * (float)W_IMG - 1.0f) * 0.5f;
        float py = ((ph[1] * inv_w + 1.0f) * (float)H_IMG - 1.0f) * 0.5f;

        float s0 = scales[i * 3 + 0], s1 = scales[i * 3 + 1], s2 = scales[i * 3 + 2];
        float smax2 = fmaxf(s0 * s0, fmaxf(s1 * s1, s2 * s2));
        float op = opac[i];
        float L = __logf(255.0f * op);

        float invtz = __builtin_amdgcn_rcpf(tz);
        float ux = pv0 * invtz, uy = pv1 * invtz;
        float u2x = fminf(ux * ux, 0.4225f);     // (1.3*TANX)^2
        float u2y = fminf(uy * uy, 0.4225f);
        float f2 = (W_IMG / (2.0f * TANX)) * invtz;   // fx == fy == 128
        f2 *= f2;
        float sw = smax2 * wb2;
        float abound = f2 * (1.0f + u2x) * sw + 0.3f;   // >= a = cov2d_xx + 0.3
        float cbound = f2 * (1.0f + u2y) * sw + 0.3f;   // >= c = cov2d_yy + 0.3
        float exb = __builtin_amdgcn_sqrtf(2.0f * L * abound) * 1.03f + 0.05f;
        float eyb = __builtin_amdgcn_sqrtf(2.0f * L * cbound) * 1.03f + 0.05f;
        if (!(tz > 0.2f) || !(L > 0.0f)) { exb = -1e9f; eyb = -1e9f; }

        bbx[i] = make_float4(px, py, exb, eyb);
        tzv[i] = tz;
    }
    __syncthreads();

    int tilex = bid & 15, tiley = bid >> 4;
    int wave = tid >> 6, lane = tid & 63;

    // ---- Phase A: cull on bound, 16 waves x 2 chunks, atomic compaction ----
    {
        float tx0 = (float)(tilex << 3), ty0 = (float)(tiley << 3);
        float tx1 = tx0 + 7.0f, ty1 = ty0 + 7.0f;
#pragma unroll
        for (int cc = 0; cc < 2; cc++) {
            int gi = (wave * 2 + cc) * 64 + lane;
            float4 b = bbx[gi];
            bool pred = (b.x >= tx0 - b.z) && (b.x <= tx1 + b.z) &&
                        (b.y >= ty0 - b.w) && (b.y <= ty1 + b.w);
            unsigned long long m = __ballot(pred);
            int n = (int)__popcll(m);
            int base = 0;
            if (lane == 0 && n) base = atomicAdd(&s_count, n);
            base = __shfl(base, 0);
            if (pred)
                lst[base + (int)__popcll(m & ((1ull << lane) - 1ull))] = (unsigned short)gi;
        }
    }
    __syncthreads();
    int c = min(s_count, CAP);

    // ---- Phase B1: gather candidate depths ----
    for (int t = tid; t < c; t += NTHR) scr[t] = tzv[lst[t]];
    __syncthreads();

    // ---- Phase B2: rank by (tz, idx) + FULL preprocess candidate + scatter ----
    for (int t = tid; t < c; t += NTHR) {
        int gi = lst[t];
        float my = scr[t];
        int rank = 0;
        int j = 0;
        for (; j + 4 <= c; j += 4) {
            float4 v = scratch4[j >> 2];
            int i0 = lst[j], i1 = lst[j + 1], i2 = lst[j + 2], i3 = lst[j + 3];
            rank += (v.x < my) || (v.x == my && i0 < gi);
            rank += (v.y < my) || (v.y == my && i1 < gi);
            rank += (v.z < my) || (v.z == my && i2 < gi);
            rank += (v.w < my) || (v.w == my && i3 < gi);
        }
        for (; j < c; j++) {
            float v = scr[j];
            rank += (v < my) || (v == my && lst[j] < gi);
        }
        float4 f1, f2v; float radf;
        full_chain(gi, means3D, opac, colors, scales, rots, viewm, projm, f1, f2v, radf);
        sf1[rank] = f1;
        sf2[rank] = f2v;
        float4 b = bbx[gi];
        spos[rank] = make_float2(b.x, b.y);
    }
    // radii: this block's 8 gaussians, exact
    if (tid < 8) {
        int g8 = bid * 8 + tid;
        float4 d1, d2; float radf;
        full_chain(g8, means3D, opac, colors, scales, rots, viewm, projm, d1, d2, radf);
        radii_out[g8] = (float)(int)radf;
    }
    __syncthreads();   // scr (stz) dead; reused as Tseg

    // ---- Phase C: segmented composite over 16 waves ----
    float gx = (float)((tilex << 3) + (lane & 7));
    float gy = (float)((tiley << 3) + (lane >> 3));
    int seglen = (c + NWAVE - 1) / NWAVE;
    int s0 = wave * seglen;
    int s1 = min(c, s0 + seglen);

    // Pass A: per-segment transmittance product (alpha-only; matches cumprod)
    float Tw = 1.0f;
    for (int t = s0; t < s1; ++t) {
        float4 f1 = sf1[t];
        float2 pp = spos[t];
        float dx = pp.x - gx, dy = pp.y - gy;
        float power = -0.5f * (f1.x * dx * dx + f1.z * dy * dy) - f1.y * dx * dy;
        if (power <= 0.0f) {
            float alpha = fminf(0.99f, f1.w * __expf(power));
            if (alpha >= ALPHA_MIN) Tw *= (1.0f - alpha);
        }
    }
    scr[wave * 64 + lane] = Tw;
    __syncthreads();

    // Pass B: composite segment from exact prefix T0
    float T0 = 1.0f;
#pragma unroll
    for (int s = 0; s < NWAVE - 1; ++s) if (s < wave) T0 *= scr[s * 64 + lane];
    float T = T0, cr = 0.0f, cg = 0.0f, cb = 0.0f, dep = 0.0f;
    int cnt = 0;
    if (!__all(T0 <= T_EPS_C)) {
        for (int t = s0; t < s1; ++t) {
            float4 f1 = sf1[t];
            float4 f2v = sf2[t];
            float2 pp = spos[t];
            float dx = pp.x - gx, dy = pp.y - gy;
            float power = -0.5f * (f1.x * dx * dx + f1.z * dy * dy) - f1.y * dx * dy;
            if (power <= 0.0f) {
                float alpha = fminf(0.99f, f1.w * __expf(power));
                if (alpha >= ALPHA_MIN) {
                    if (T > T_EPS_C) {
                        float w = alpha * T;
                        cr += w * f2v.x; cg += w * f2v.y; cb += w * f2v.z;
                        dep += w * f2v.w;
                        cnt++;
                    }
                    T *= (1.0f - alpha);
                    if (__all(T <= T_EPS_C)) break;   // exact: final T from Tseg products
                }
            }
        }
    }
    accv[wave * 64 + lane] = make_float4(cr, cg, cb, dep);
    ((int*)lst)[wave * 64 + lane] = cnt;    // lst dead: overlay (1024 ints = 4 KB)
    __syncthreads();

    // ---- Final: wave 0 reduces 16 partials per pixel, adds bg, writes out ----
    if (tid < 64) {
        float crr = 0.0f, cgg = 0.0f, cbb = 0.0f, dpp = 0.0f, Tf = 1.0f;
        int cnt_t = 0;
        const int* an = (const int*)lst;
#pragma unroll
        for (int s = 0; s < NWAVE; ++s) {
            float4 a = accv[s * 64 + tid];
            crr += a.x; cgg += a.y; cbb += a.z; dpp += a.w;
            cnt_t += an[s * 64 + tid];
            Tf *= scr[s * 64 + tid];
        }
        crr += Tf * bg[0]; cgg += Tf * bg[1]; cbb += Tf * bg[2];

        int pid = ((tiley << 3) + (tid >> 3)) * W_IMG + (tilex << 3) + (tid & 7);
        out[0 * NPIX + pid] = crr;
        out[1 * NPIX + pid] = cgg;
        out[2 * NPIX + pid] = cbb;
        out[3 * NPIX + pid] = dpp;
        out[4 * NPIX + N_G + pid] = (float)cnt_t;
    }
}

extern "C" void kernel_launch(void* const* d_in, const int* in_sizes, int n_in,
                              void* d_out, int out_size, void* d_ws, size_t ws_size,
                              hipStream_t stream) {
    const float* bg      = (const float*)d_in[0];
    const float* means3D = (const float*)d_in[1];
    const float* opac    = (const float*)d_in[3];
    const float* colors  = (const float*)d_in[4];
    const float* scales  = (const float*)d_in[5];
    const float* rots    = (const float*)d_in[6];
    const float* viewm   = (const float*)d_in[7];
    const float* projm   = (const float*)d_in[8];

    gs_fused<<<256, NTHR, 0, stream>>>(means3D, opac, colors, scales, rots,
                                       viewm, projm, bg, (float*)d_out);
}